// Round 13
// baseline (121.238 us; speedup 1.0000x reference)
//
#include <hip/hip_runtime.h>
#include <hip/hip_fp16.h>
#include <cstddef>
#include <type_traits>

// GCN encoder: 3-layer (GCNConv 128->128, GCNConv 128->128, Linear 128->64).
// 5 launches: prep(Wt+zero) -> [bucket_p1 || G1] -> build_p2(+dinv) ->
//   [agg1(weighted) -> LDS -> xW2, *dinv] -> [agg2(pure add) -> LDS -> xW3+b3+relu]
// R12 lesson: agg is at the ~5 TB/s random-gather wall (5 structural variants
// all ~42us) — this round attacks the prologue via overlap + packed buckets.
// gbucket entry packed: (src<<8)|(dst&255)  [requires N < 65536].

typedef _Float16 half8 __attribute__((ext_vector_type(8)));
typedef float f32x4 __attribute__((ext_vector_type(4)));

constexpr int CAP = 4608;  // bucket capacity; mean 4096, sigma ~64

// ---------------- prep: transpose weights -> fp16, zero gcount --------------
__global__ __launch_bounds__(256) void prep(const float* __restrict__ W1,
                                            const float* __restrict__ W2,
                                            const float* __restrict__ W3,
                                            __half* __restrict__ w1t,
                                            __half* __restrict__ w2t,
                                            __half* __restrict__ w3t,
                                            int* __restrict__ gcount, int nb) {
    int b = blockIdx.x;
    if (b == 0 && threadIdx.x < nb) gcount[threadIdx.x] = 0;
    const float* W;
    __half* Wt;
    int ncol, i;
    if (b < 64) { W = W1; Wt = w1t; ncol = 128; i = b * 256 + threadIdx.x; }
    else if (b < 128) { W = W2; Wt = w2t; ncol = 128; i = (b - 64) * 256 + threadIdx.x; }
    else { W = W3; Wt = w3t; ncol = 64; i = (b - 128) * 256 + threadIdx.x; }
    if (i < 128 * ncol) {
        int k = i / ncol, c = i - k * ncol;
        Wt[c * 128 + k] = __float2half(W[i]);
    }
}

// ---------------- G1 tile: fp32 A in, fp16 out (no prescale) ----------------
// Operand swap (Wt frag = A-op, row frag = B-op): lane l holds
// C[r0 + (l&15)][colbase + (l>>4)*4 + reg] -> packed fp16 stores.
__device__ __forceinline__ void gemm_tile_xf32(const float* __restrict__ A,
                                               const __half* __restrict__ Wt,
                                               __half* __restrict__ C, int M,
                                               int tile, int t) {
    constexpr int NC = 4;
    const int w = t >> 6, l = t & 63;
    const int lr = l & 15, kg = l >> 4;
    const int rh = w >> 1, ch = w & 1;
    const int r0 = tile * 64 + rh * 32;

    half8 wf[NC][4];
#pragma unroll
    for (int c = 0; c < NC; ++c)
#pragma unroll
        for (int ks = 0; ks < 4; ++ks)
            wf[c][ks] = *(const half8*)&Wt[(size_t)((ch * NC + c) * 16 + lr) * 128 +
                                           ks * 32 + kg * 8];

    f32x4 acc[2][NC];
#pragma unroll
    for (int rt = 0; rt < 2; ++rt)
#pragma unroll
        for (int c = 0; c < NC; ++c) acc[rt][c] = (f32x4){0.f, 0.f, 0.f, 0.f};

    const int row0 = r0 + lr, row1 = r0 + 16 + lr;
    const bool ok0 = row0 < M, ok1 = row1 < M;
#pragma unroll
    for (int ks = 0; ks < 4; ++ks) {
        half8 af0 = (half8)(_Float16)0, af1 = (half8)(_Float16)0;
        if (ok0) {
            float4 p = *(const float4*)&A[(size_t)row0 * 128 + ks * 32 + kg * 8];
            float4 q = *(const float4*)&A[(size_t)row0 * 128 + ks * 32 + kg * 8 + 4];
            af0[0] = (_Float16)p.x; af0[1] = (_Float16)p.y;
            af0[2] = (_Float16)p.z; af0[3] = (_Float16)p.w;
            af0[4] = (_Float16)q.x; af0[5] = (_Float16)q.y;
            af0[6] = (_Float16)q.z; af0[7] = (_Float16)q.w;
        }
        if (ok1) {
            float4 p = *(const float4*)&A[(size_t)row1 * 128 + ks * 32 + kg * 8];
            float4 q = *(const float4*)&A[(size_t)row1 * 128 + ks * 32 + kg * 8 + 4];
            af1[0] = (_Float16)p.x; af1[1] = (_Float16)p.y;
            af1[2] = (_Float16)p.z; af1[3] = (_Float16)p.w;
            af1[4] = (_Float16)q.x; af1[5] = (_Float16)q.y;
            af1[6] = (_Float16)q.z; af1[7] = (_Float16)q.w;
        }
#pragma unroll
        for (int c = 0; c < NC; ++c) {
            acc[0][c] = __builtin_amdgcn_mfma_f32_16x16x32_f16(wf[c][ks], af0, acc[0][c], 0, 0, 0);
            acc[1][c] = __builtin_amdgcn_mfma_f32_16x16x32_f16(wf[c][ks], af1, acc[1][c], 0, 0, 0);
        }
    }

#pragma unroll
    for (int rt = 0; rt < 2; ++rt) {
        int row = r0 + rt * 16 + lr;
        if (row < M) {
#pragma unroll
            for (int c = 0; c < NC; ++c) {
                int col = (ch * NC + c) * 16 + kg * 4;
                __half2 p0 = __floats2half2_rn(acc[rt][c][0], acc[rt][c][1]);
                __half2 p1 = __floats2half2_rn(acc[rt][c][2], acc[rt][c][3]);
                *(int2*)&C[(size_t)row * 128 + col] = make_int2(*(int*)&p0, *(int*)&p1);
            }
        }
    }
}

// ---------------- fused: bucket edges (blocks < nbkt) || GEMM1 (rest) -------
// Bucket part: 256 threads x 8 edges; LDS histogram over nb buckets -> one
// global atomic per bucket per block -> packed (src<<8)|dstlocal appends.
__global__ __launch_bounds__(256) void bucket_and_g1(const int* __restrict__ src,
                                                     const int* __restrict__ dst,
                                                     int* __restrict__ gcount,
                                                     int* __restrict__ gbucket,
                                                     int nb, int e, int nbkt,
                                                     const float* __restrict__ x,
                                                     const __half* __restrict__ w1t,
                                                     __half* __restrict__ g1buf, int n) {
    const int bid = blockIdx.x, t = threadIdx.x;
    if (bid >= nbkt) {
        gemm_tile_xf32(x, w1t, g1buf, n, bid - nbkt, t);
        return;
    }
    __shared__ int lcnt[256];
    __shared__ int lbase[256];
    if (t < nb) lcnt[t] = 0;
    __syncthreads();

    int base = bid * 2048 + t * 8;
    int d[8], s[8], pb[8], pp[8];
    if (base + 8 <= e) {
        *(int4*)&d[0] = *(const int4*)&dst[base];
        *(int4*)&d[4] = *(const int4*)&dst[base + 4];
        *(int4*)&s[0] = *(const int4*)&src[base];
        *(int4*)&s[4] = *(const int4*)&src[base + 4];
    } else {
#pragma unroll
        for (int u = 0; u < 8; ++u) {
            d[u] = (base + u < e) ? dst[base + u] : -1;
            s[u] = (base + u < e) ? src[base + u] : 0;
        }
    }
#pragma unroll
    for (int u = 0; u < 8; ++u) {
        if (d[u] >= 0) {
            pb[u] = d[u] >> 8;
            pp[u] = atomicAdd(&lcnt[pb[u]], 1);
        }
    }
    __syncthreads();
    if (t < nb) lbase[t] = lcnt[t] ? atomicAdd(&gcount[t], lcnt[t]) : 0;
    __syncthreads();
#pragma unroll
    for (int u = 0; u < 8; ++u) {
        if (d[u] >= 0) {
            int p = lbase[pb[u]] + pp[u];
            if (p < CAP)
                gbucket[(size_t)pb[u] * CAP + p] = (s[u] << 8) | (d[u] & 255);
        }
    }
}

// ---------------- build CSR: offs, dinv, eidx (one block per bucket) --------
__global__ __launch_bounds__(256) void build_p2(const int* __restrict__ gcount,
                                                const int* __restrict__ gbucket,
                                                int* __restrict__ offs,
                                                float* __restrict__ dinv,
                                                int* __restrict__ eidx, int n, int nb) {
    __shared__ int srcS[CAP];
    __shared__ int sc[256];
    __shared__ int cur[256];
    const int bid = blockIdx.x, t = threadIdx.x;
    int node0 = bid << 8;

    int own = (t < nb) ? gcount[t] : 0;
    sc[t] = own;
    __syncthreads();
    for (int d = 1; d < 256; d <<= 1) {
        int u = (t >= d) ? sc[t - d] : 0;
        __syncthreads();
        sc[t] += u;
        __syncthreads();
    }
    cur[t] = sc[t] - own;
    if (bid == 0 && t == 0) offs[n] = sc[255];
    __syncthreads();
    int gb = cur[bid];
    int cnt = min(gcount[bid], CAP);
    __syncthreads();

    cur[t] = 0;
    __syncthreads();
    const int* gbp = gbucket + (size_t)bid * CAP;
    for (int i = t; i < cnt; i += 256) atomicAdd(&cur[gbp[i] & 255], 1);
    __syncthreads();
    own = cur[t];
    sc[t] = own;
    __syncthreads();
    for (int d = 1; d < 256; d <<= 1) {
        int u = (t >= d) ? sc[t - d] : 0;
        __syncthreads();
        sc[t] += u;
        __syncthreads();
    }
    int excl = sc[t] - own;
    int node = node0 + t;
    if (node < n) {
        offs[node] = gb + excl;
        dinv[node] = rsqrtf((float)(own + 1));  // +1 self-loop
    }
    cur[t] = excl;
    __syncthreads();
    for (int i = t; i < cnt; i += 256) {
        int pr = gbp[i];
        int pos = atomicAdd(&cur[pr & 255], 1);
        srcS[pos] = pr >> 8;
    }
    __syncthreads();
    for (int i = t; i < cnt; i += 256) eidx[gb + i] = srcS[i];
}

// ---------------- fused agg + GEMM ------------------------------------------
// Block = 16 nodes, 16 lanes/node, int4 gathers.
// IN_PRE:  rows pre-scaled -> pure-add loop (16-deep); result *= dv.
// !IN_PRE: weighted loop (dinv[s]*dv per edge, 8-deep).
// OUT_PRE: GEMM epilogue rows *= dinv[row]. EPI: +biasG, relu (fp32 out).
template <int N2, bool EPI, typename OT, bool IN_PRE, bool OUT_PRE>
__global__ __launch_bounds__(256) void agg_gemm(const __half* __restrict__ g,
                                                const float* __restrict__ dinv,
                                                const int* __restrict__ offs,
                                                const int* __restrict__ eidx,
                                                const float* __restrict__ biasA,
                                                const __half* __restrict__ Wt,
                                                const float* __restrict__ biasG,
                                                OT* __restrict__ C, int n) {
    __shared__ alignas(16) char hs[16 * 256];  // 16 rows x 128 fp16, swizzled
    const int t = threadIdx.x;
    const int node0 = blockIdx.x * 16;
    constexpr int UN = IN_PRE ? 16 : 8;

    {
        int row = t >> 4;
        int lane = t & 15;
        int node = node0 + row;
        int bo = (lane * 16) ^ ((row & 7) << 4);
        if (node < n) {
            const int4* h4 = (const int4*)g;
            float dv = dinv[node];
            int4 sp = h4[(size_t)node * 16 + lane];
            float a0, a1, a2, a3, a4, a5, a6, a7;
            {
                float nm = IN_PRE ? 1.f : dv * dv;
                float2 f0 = __half22float2(*(__half2*)&sp.x);
                float2 f1 = __half22float2(*(__half2*)&sp.y);
                float2 f2 = __half22float2(*(__half2*)&sp.z);
                float2 f3 = __half22float2(*(__half2*)&sp.w);
                a0 = f0.x * nm; a1 = f0.y * nm; a2 = f1.x * nm; a3 = f1.y * nm;
                a4 = f2.x * nm; a5 = f2.y * nm; a6 = f3.x * nm; a7 = f3.y * nm;
            }
            int beg = offs[node], end = offs[node + 1];
            int j = beg;
            for (; j + UN <= end; j += UN) {
                int s[UN];
                float wg[UN];
                int4 hv[UN];
#pragma unroll
                for (int u = 0; u < UN; ++u) s[u] = eidx[j + u];
#pragma unroll
                for (int u = 0; u < UN; ++u) {
                    if constexpr (!IN_PRE) wg[u] = dinv[s[u]];
                    hv[u] = h4[(size_t)s[u] * 16 + lane];
                }
#pragma unroll
                for (int u = 0; u < UN; ++u) {
                    float2 g0 = __half22float2(*(__half2*)&hv[u].x);
                    float2 g1 = __half22float2(*(__half2*)&hv[u].y);
                    float2 g2 = __half22float2(*(__half2*)&hv[u].z);
                    float2 g3 = __half22float2(*(__half2*)&hv[u].w);
                    if constexpr (IN_PRE) {
                        a0 += g0.x; a1 += g0.y; a2 += g1.x; a3 += g1.y;
                        a4 += g2.x; a5 += g2.y; a6 += g3.x; a7 += g3.y;
                    } else {
                        float wu = wg[u] * dv;
                        a0 = fmaf(g0.x, wu, a0); a1 = fmaf(g0.y, wu, a1);
                        a2 = fmaf(g1.x, wu, a2); a3 = fmaf(g1.y, wu, a3);
                        a4 = fmaf(g2.x, wu, a4); a5 = fmaf(g2.y, wu, a5);
                        a6 = fmaf(g3.x, wu, a6); a7 = fmaf(g3.y, wu, a7);
                    }
                }
            }
            if (j < end) {
                int s[UN];
                float wg[UN];
                int4 hv[UN];
#pragma unroll
                for (int u = 0; u < UN; ++u) {
                    int idx = j + u;
                    s[u] = eidx[idx < end ? idx : end - 1];
                }
#pragma unroll
                for (int u = 0; u < UN; ++u) {
                    if constexpr (IN_PRE) wg[u] = (j + u < end) ? 1.f : 0.f;
                    else                  wg[u] = (j + u < end) ? dinv[s[u]] : 0.f;
                    hv[u] = h4[(size_t)s[u] * 16 + lane];
                }
#pragma unroll
                for (int u = 0; u < UN; ++u) {
                    float wu = IN_PRE ? wg[u] : wg[u] * dv;
                    float2 g0 = __half22float2(*(__half2*)&hv[u].x);
                    float2 g1 = __half22float2(*(__half2*)&hv[u].y);
                    float2 g2 = __half22float2(*(__half2*)&hv[u].z);
                    float2 g3 = __half22float2(*(__half2*)&hv[u].w);
                    a0 = fmaf(g0.x, wu, a0); a1 = fmaf(g0.y, wu, a1);
                    a2 = fmaf(g1.x, wu, a2); a3 = fmaf(g1.y, wu, a3);
                    a4 = fmaf(g2.x, wu, a4); a5 = fmaf(g2.y, wu, a5);
                    a6 = fmaf(g3.x, wu, a6); a7 = fmaf(g3.y, wu, a7);
                }
            }
            if constexpr (IN_PRE) {
                a0 *= dv; a1 *= dv; a2 *= dv; a3 *= dv;
                a4 *= dv; a5 *= dv; a6 *= dv; a7 *= dv;
            }
            float4 b0 = *(const float4*)&biasA[lane * 8];
            float4 b1 = *(const float4*)&biasA[lane * 8 + 4];
            a0 = fmaxf(a0 + b0.x, 0.f); a1 = fmaxf(a1 + b0.y, 0.f);
            a2 = fmaxf(a2 + b0.z, 0.f); a3 = fmaxf(a3 + b0.w, 0.f);
            a4 = fmaxf(a4 + b1.x, 0.f); a5 = fmaxf(a5 + b1.y, 0.f);
            a6 = fmaxf(a6 + b1.z, 0.f); a7 = fmaxf(a7 + b1.w, 0.f);
            __half2 o0 = __floats2half2_rn(a0, a1);
            __half2 o1 = __floats2half2_rn(a2, a3);
            __half2 o2 = __floats2half2_rn(a4, a5);
            __half2 o3 = __floats2half2_rn(a6, a7);
            *(int4*)&hs[row * 256 + bo] =
                make_int4(*(int*)&o0, *(int*)&o1, *(int*)&o2, *(int*)&o3);
        } else {
            *(int4*)&hs[row * 256 + bo] = make_int4(0, 0, 0, 0);
        }
    }
    __syncthreads();

    // ---- phase 2: 16-row GEMM from LDS ----
    constexpr int NW = N2 / 4;
    constexpr int NC = NW / 16;
    const int w = t >> 6, l = t & 63;
    const int lr = l & 15, kg = l >> 4;

    half8 wf[NC][4];
#pragma unroll
    for (int c = 0; c < NC; ++c)
#pragma unroll
        for (int ks = 0; ks < 4; ++ks)
            wf[c][ks] = *(const half8*)&Wt[(size_t)(w * NW + c * 16 + lr) * 128 +
                                           ks * 32 + kg * 8];

    half8 af[4];
#pragma unroll
    for (int ks = 0; ks < 4; ++ks) {
        int bo = (ks * 64 + kg * 16) ^ ((lr & 7) << 4);
        af[ks] = *(const half8*)&hs[lr * 256 + bo];
    }

    f32x4 acc[NC];
#pragma unroll
    for (int c = 0; c < NC; ++c) acc[c] = (f32x4){0.f, 0.f, 0.f, 0.f};
#pragma unroll
    for (int ks = 0; ks < 4; ++ks)
#pragma unroll
        for (int c = 0; c < NC; ++c)
            acc[c] = __builtin_amdgcn_mfma_f32_16x16x32_f16(wf[c][ks], af[ks], acc[c], 0, 0, 0);

    int row = node0 + lr;
    if (row < n) {
        float dvr = OUT_PRE ? dinv[row] : 1.f;
#pragma unroll
        for (int c = 0; c < NC; ++c) {
            int col = w * NW + c * 16 + kg * 4;
            float v0 = acc[c][0], v1 = acc[c][1], v2 = acc[c][2], v3 = acc[c][3];
            if constexpr (EPI) {
                float4 bv = *(const float4*)&biasG[col];
                v0 = fmaxf(v0 + bv.x, 0.f);
                v1 = fmaxf(v1 + bv.y, 0.f);
                v2 = fmaxf(v2 + bv.z, 0.f);
                v3 = fmaxf(v3 + bv.w, 0.f);
            }
            if constexpr (OUT_PRE) { v0 *= dvr; v1 *= dvr; v2 *= dvr; v3 *= dvr; }
            if constexpr (std::is_same_v<OT, float>) {
                *(float4*)&C[(size_t)row * N2 + col] = make_float4(v0, v1, v2, v3);
            } else {
                __half2 p0 = __floats2half2_rn(v0, v1);
                __half2 p1 = __floats2half2_rn(v2, v3);
                *(int2*)&C[(size_t)row * N2 + col] = make_int2(*(int*)&p0, *(int*)&p1);
            }
        }
    }
}

extern "C" void kernel_launch(void* const* d_in, const int* in_sizes, int n_in,
                              void* d_out, int out_size, void* d_ws, size_t ws_size,
                              hipStream_t stream) {
    const float* x  = (const float*)d_in[0];
    const int* ei   = (const int*)d_in[1];
    const float* W1 = (const float*)d_in[2];
    const float* b1 = (const float*)d_in[3];
    const float* W2 = (const float*)d_in[4];
    const float* b2 = (const float*)d_in[5];
    const float* W3 = (const float*)d_in[6];
    const float* b3 = (const float*)d_in[7];
    float* out = (float*)d_out;

    const int N = in_sizes[0] / 128;   // assumed < 65536 (bucket packing)
    const int E = in_sizes[1] / 2;
    const int* esrc = ei;
    const int* edst = ei + E;
    const int nb = (N + 255) >> 8;     // 196 buckets (must be <=256)

    char* w = (char*)d_ws;
    size_t off = 0;
    auto alloc = [&](size_t bytes) {
        void* p = w + off;
        off = (off + bytes + 255) & ~(size_t)255;
        return p;
    };
    int*    gcount  = (int*)alloc((size_t)nb * 4);
    int*    gbucket = (int*)alloc((size_t)nb * CAP * 4);
    int*    offs    = (int*)alloc((size_t)(N + 1) * 4);
    float*  dinv    = (float*)alloc((size_t)N * 4);
    int*    eidx    = (int*)alloc((size_t)E * 4);
    __half* w1t     = (__half*)alloc(128 * 128 * 2);
    __half* w2t     = (__half*)alloc(128 * 128 * 2);
    __half* w3t     = (__half*)alloc(64 * 128 * 2);
    __half* g1buf   = (__half*)alloc((size_t)N * 128 * 2);
    __half* g2buf   = (__half*)alloc((size_t)N * 128 * 2);
    (void)ws_size;

    const int gemm_blocks = (N + 63) / 64;     // 782
    const int nbkt = (E + 2047) / 2048;        // 391 bucket blocks
    const int agg_blocks = (N + 15) / 16;      // 3125

    prep<<<160, 256, 0, stream>>>(W1, W2, W3, w1t, w2t, w3t, gcount, nb);
    bucket_and_g1<<<nbkt + gemm_blocks, 256, 0, stream>>>(
        esrc, edst, gcount, gbucket, nb, E, nbkt, x, w1t, g1buf, N);
    build_p2<<<nb, 256, 0, stream>>>(gcount, gbucket, offs, dinv, eidx, N, nb);
    // layer1: weighted agg + xW2; output rows *= dinv (pre-scale for layer2)
    agg_gemm<128, false, __half, false, true><<<agg_blocks, 256, 0, stream>>>(
        g1buf, dinv, offs, eidx, b1, w2t, nullptr, g2buf, N);
    // layer2: pure-add agg + xW3 + b3 + relu -> fp32 out
    agg_gemm<64, true, float, true, false><<<agg_blocks, 256, 0, stream>>>(
        g2buf, dinv, offs, eidx, b2, w3t, b3, out, N);
}

// Round 14
// 114.782 us; speedup vs baseline: 1.0563x; 1.0563x over previous
//
#include <hip/hip_runtime.h>
#include <hip/hip_fp16.h>
#include <cstddef>
#include <type_traits>

// GCN encoder: 3-layer (GCNConv 128->128, GCNConv 128->128, Linear 128->64).
// 5 launches: prep(Wt+zero) -> bucket_p1 -> [buildCSR || G1(fp32 in)] ->
//   [agg1(weighted) -> LDS -> xW2, out *= dinv[row]]  (g2buf rows pre-scaled)
//   [agg2(pure add, 16-deep) -> LDS -> xW3+b3+relu -> d_out]
// Best-measured configuration (R11: 115.2us). agg kernels are at the XCD
// fabric wall: 82 MB L2-miss traffic @ ~2 TB/s = 41us each (5 structural
// variants all 42+-0.5us; MSHR x L3-latency bound, not VALU/occupancy).

typedef _Float16 half8 __attribute__((ext_vector_type(8)));
typedef float f32x4 __attribute__((ext_vector_type(4)));

constexpr int CAP = 4608;  // bucket capacity; mean 4096, sigma ~64

// ---------------- prep: transpose weights -> fp16, zero gcount --------------
__global__ __launch_bounds__(256) void prep(const float* __restrict__ W1,
                                            const float* __restrict__ W2,
                                            const float* __restrict__ W3,
                                            __half* __restrict__ w1t,
                                            __half* __restrict__ w2t,
                                            __half* __restrict__ w3t,
                                            int* __restrict__ gcount, int nb) {
    int b = blockIdx.x;
    if (b == 0 && threadIdx.x < nb) gcount[threadIdx.x] = 0;
    const float* W;
    __half* Wt;
    int ncol, i;
    if (b < 64) { W = W1; Wt = w1t; ncol = 128; i = b * 256 + threadIdx.x; }
    else if (b < 128) { W = W2; Wt = w2t; ncol = 128; i = (b - 64) * 256 + threadIdx.x; }
    else { W = W3; Wt = w3t; ncol = 64; i = (b - 128) * 256 + threadIdx.x; }
    if (i < 128 * ncol) {
        int k = i / ncol, c = i - k * ncol;
        Wt[c * 128 + k] = __float2half(W[i]);
    }
}

// ---------------- P1: bucket edges by dst>>8 --------------------------------
__global__ __launch_bounds__(1024) void bucket_p1(const int* __restrict__ src,
                                                  const int* __restrict__ dst,
                                                  int* __restrict__ gcount,
                                                  int2* __restrict__ gbucket,
                                                  int nb, int e) {
    __shared__ int lcnt[256];
    __shared__ int lbase[256];
    int t = threadIdx.x;
    if (t < nb) lcnt[t] = 0;
    __syncthreads();

    int base = blockIdx.x * 8192 + t * 8;
    int d[8], s[8], pb[8], pp[8];
    if (base + 8 <= e) {
        *(int4*)&d[0] = *(const int4*)&dst[base];
        *(int4*)&d[4] = *(const int4*)&dst[base + 4];
        *(int4*)&s[0] = *(const int4*)&src[base];
        *(int4*)&s[4] = *(const int4*)&src[base + 4];
    } else {
#pragma unroll
        for (int u = 0; u < 8; ++u) {
            d[u] = (base + u < e) ? dst[base + u] : -1;
            s[u] = (base + u < e) ? src[base + u] : 0;
        }
    }
#pragma unroll
    for (int u = 0; u < 8; ++u) {
        if (d[u] >= 0) {
            pb[u] = d[u] >> 8;
            pp[u] = atomicAdd(&lcnt[pb[u]], 1);
        }
    }
    __syncthreads();
    if (t < nb) lbase[t] = lcnt[t] ? atomicAdd(&gcount[t], lcnt[t]) : 0;
    __syncthreads();
#pragma unroll
    for (int u = 0; u < 8; ++u) {
        if (d[u] >= 0) {
            int p = lbase[pb[u]] + pp[u];
            if (p < CAP) gbucket[(size_t)pb[u] * CAP + p] = make_int2(d[u], s[u]);
        }
    }
}

// ---------------- G1 tile: fp32 A input, in-register cvt, fp16 out ----------
__device__ __forceinline__ void gemm_tile_xf32(const float* __restrict__ A,
                                               const __half* __restrict__ Wt,
                                               __half* __restrict__ C, int M,
                                               int tile, int t) {
    constexpr int NC = 4;
    const int w = t >> 6, l = t & 63;
    const int lr = l & 15, kg = l >> 4;
    const int rh = w >> 1, ch = w & 1;
    const int r0 = tile * 64 + rh * 32;

    half8 wf[NC][4];
#pragma unroll
    for (int c = 0; c < NC; ++c)
#pragma unroll
        for (int ks = 0; ks < 4; ++ks)
            wf[c][ks] = *(const half8*)&Wt[(size_t)((ch * NC + c) * 16 + lr) * 128 +
                                           ks * 32 + kg * 8];

    f32x4 acc[2][NC];
#pragma unroll
    for (int rt = 0; rt < 2; ++rt)
#pragma unroll
        for (int c = 0; c < NC; ++c) acc[rt][c] = (f32x4){0.f, 0.f, 0.f, 0.f};

    const int row0 = r0 + lr, row1 = r0 + 16 + lr;
    const bool ok0 = row0 < M, ok1 = row1 < M;
#pragma unroll
    for (int ks = 0; ks < 4; ++ks) {
        half8 af0 = (half8)(_Float16)0, af1 = (half8)(_Float16)0;
        if (ok0) {
            float4 p = *(const float4*)&A[(size_t)row0 * 128 + ks * 32 + kg * 8];
            float4 q = *(const float4*)&A[(size_t)row0 * 128 + ks * 32 + kg * 8 + 4];
            af0[0] = (_Float16)p.x; af0[1] = (_Float16)p.y;
            af0[2] = (_Float16)p.z; af0[3] = (_Float16)p.w;
            af0[4] = (_Float16)q.x; af0[5] = (_Float16)q.y;
            af0[6] = (_Float16)q.z; af0[7] = (_Float16)q.w;
        }
        if (ok1) {
            float4 p = *(const float4*)&A[(size_t)row1 * 128 + ks * 32 + kg * 8];
            float4 q = *(const float4*)&A[(size_t)row1 * 128 + ks * 32 + kg * 8 + 4];
            af1[0] = (_Float16)p.x; af1[1] = (_Float16)p.y;
            af1[2] = (_Float16)p.z; af1[3] = (_Float16)p.w;
            af1[4] = (_Float16)q.x; af1[5] = (_Float16)q.y;
            af1[6] = (_Float16)q.z; af1[7] = (_Float16)q.w;
        }
#pragma unroll
        for (int c = 0; c < NC; ++c) {
            acc[0][c] = __builtin_amdgcn_mfma_f32_16x16x32_f16(wf[c][ks], af0, acc[0][c], 0, 0, 0);
            acc[1][c] = __builtin_amdgcn_mfma_f32_16x16x32_f16(wf[c][ks], af1, acc[1][c], 0, 0, 0);
        }
    }

#pragma unroll
    for (int rt = 0; rt < 2; ++rt) {
        int row = r0 + rt * 16 + lr;
        if (row < M) {
#pragma unroll
            for (int c = 0; c < NC; ++c) {
                int col = (ch * NC + c) * 16 + kg * 4;
                __half2 p0 = __floats2half2_rn(acc[rt][c][0], acc[rt][c][1]);
                __half2 p1 = __floats2half2_rn(acc[rt][c][2], acc[rt][c][3]);
                *(int2*)&C[(size_t)row * 128 + col] = make_int2(*(int*)&p0, *(int*)&p1);
            }
        }
    }
}

// ---------------- fused: build CSR (blocks < nb) || GEMM1 (rest) ------------
__global__ __launch_bounds__(256) void build_and_g1(const int* __restrict__ gcount,
                                                    const int2* __restrict__ gbucket,
                                                    int* __restrict__ offs,
                                                    float* __restrict__ dinv,
                                                    int* __restrict__ eidx,
                                                    const float* __restrict__ x,
                                                    const __half* __restrict__ w1t,
                                                    __half* __restrict__ g1buf,
                                                    int n, int nb) {
    __shared__ int srcS[CAP];
    __shared__ int sc[256];
    __shared__ int cur[256];
    const int bid = blockIdx.x, t = threadIdx.x;

    if (bid >= nb) {
        gemm_tile_xf32(x, w1t, g1buf, n, bid - nb, t);
        return;
    }

    int node0 = bid << 8;
    int own = (t < nb) ? gcount[t] : 0;
    sc[t] = own;
    __syncthreads();
    for (int d = 1; d < 256; d <<= 1) {
        int u = (t >= d) ? sc[t - d] : 0;
        __syncthreads();
        sc[t] += u;
        __syncthreads();
    }
    cur[t] = sc[t] - own;
    if (bid == 0 && t == 0) offs[n] = sc[255];
    __syncthreads();
    int gb = cur[bid];
    int cnt = min(gcount[bid], CAP);
    __syncthreads();

    cur[t] = 0;
    __syncthreads();
    const int2* gbp = gbucket + (size_t)bid * CAP;
    for (int i = t; i < cnt; i += 256) {
        int2 pr = gbp[i];
        atomicAdd(&cur[pr.x - node0], 1);
    }
    __syncthreads();
    own = cur[t];
    sc[t] = own;
    __syncthreads();
    for (int d = 1; d < 256; d <<= 1) {
        int u = (t >= d) ? sc[t - d] : 0;
        __syncthreads();
        sc[t] += u;
        __syncthreads();
    }
    int excl = sc[t] - own;
    int node = node0 + t;
    if (node < n) {
        offs[node] = gb + excl;
        dinv[node] = rsqrtf((float)(own + 1));  // +1 self-loop
    }
    cur[t] = excl;
    __syncthreads();
    for (int i = t; i < cnt; i += 256) {
        int2 pr = gbp[i];
        int pos = atomicAdd(&cur[pr.x - node0], 1);
        srcS[pos] = pr.y;
    }
    __syncthreads();
    for (int i = t; i < cnt; i += 256) eidx[gb + i] = srcS[i];
}

// ---------------- fused agg + GEMM ------------------------------------------
// Block = 16 nodes. Phase 1: aggregate -> bias+relu -> fp16 tile in swizzled
// LDS. Phase 2: 4 waves MFMA the 16-row tile x Wt.
// IN_PRE:  input rows pre-scaled r[s]=h[s]*dinv[s] -> pure-add loop, 16-deep.
// OUT_PRE: GEMM output rows *= dinv[row] before fp16 store.
template <int N2, bool EPI, typename OT, bool IN_PRE, bool OUT_PRE>
__global__ __launch_bounds__(256) void agg_gemm(const __half* __restrict__ g,
                                                const float* __restrict__ dinv,
                                                const int* __restrict__ offs,
                                                const int* __restrict__ eidx,
                                                const float* __restrict__ biasA,
                                                const __half* __restrict__ Wt,
                                                const float* __restrict__ biasG,
                                                OT* __restrict__ C, int n) {
    __shared__ alignas(16) char hs[16 * 256];  // 16 rows x 128 fp16, swizzled
    const int t = threadIdx.x;
    const int node0 = blockIdx.x * 16;
    constexpr int UN = IN_PRE ? 16 : 8;

    {
        int row = t >> 4;
        int lane = t & 15;
        int node = node0 + row;
        int bo = (lane * 16) ^ ((row & 7) << 4);
        if (node < n) {
            const int4* h4 = (const int4*)g;
            float dv = dinv[node];
            int4 sp = h4[(size_t)node * 16 + lane];
            float a0, a1, a2, a3, a4, a5, a6, a7;
            {
                float nm = IN_PRE ? 1.f : dv * dv;
                float2 f0 = __half22float2(*(__half2*)&sp.x);
                float2 f1 = __half22float2(*(__half2*)&sp.y);
                float2 f2 = __half22float2(*(__half2*)&sp.z);
                float2 f3 = __half22float2(*(__half2*)&sp.w);
                a0 = f0.x * nm; a1 = f0.y * nm; a2 = f1.x * nm; a3 = f1.y * nm;
                a4 = f2.x * nm; a5 = f2.y * nm; a6 = f3.x * nm; a7 = f3.y * nm;
            }
            int beg = offs[node], end = offs[node + 1];
            int j = beg;
            for (; j + UN <= end; j += UN) {
                int s[UN];
                float wg[UN];
                int4 hv[UN];
#pragma unroll
                for (int u = 0; u < UN; ++u) s[u] = eidx[j + u];
#pragma unroll
                for (int u = 0; u < UN; ++u) {
                    if constexpr (!IN_PRE) wg[u] = dinv[s[u]];
                    hv[u] = h4[(size_t)s[u] * 16 + lane];
                }
#pragma unroll
                for (int u = 0; u < UN; ++u) {
                    float2 g0 = __half22float2(*(__half2*)&hv[u].x);
                    float2 g1 = __half22float2(*(__half2*)&hv[u].y);
                    float2 g2 = __half22float2(*(__half2*)&hv[u].z);
                    float2 g3 = __half22float2(*(__half2*)&hv[u].w);
                    if constexpr (IN_PRE) {
                        a0 += g0.x; a1 += g0.y; a2 += g1.x; a3 += g1.y;
                        a4 += g2.x; a5 += g2.y; a6 += g3.x; a7 += g3.y;
                    } else {
                        float wu = wg[u] * dv;
                        a0 = fmaf(g0.x, wu, a0); a1 = fmaf(g0.y, wu, a1);
                        a2 = fmaf(g1.x, wu, a2); a3 = fmaf(g1.y, wu, a3);
                        a4 = fmaf(g2.x, wu, a4); a5 = fmaf(g2.y, wu, a5);
                        a6 = fmaf(g3.x, wu, a6); a7 = fmaf(g3.y, wu, a7);
                    }
                }
            }
            if (j < end) {
                int s[UN];
                float wg[UN];
                int4 hv[UN];
#pragma unroll
                for (int u = 0; u < UN; ++u) {
                    int idx = j + u;
                    s[u] = eidx[idx < end ? idx : end - 1];
                }
#pragma unroll
                for (int u = 0; u < UN; ++u) {
                    if constexpr (IN_PRE) wg[u] = (j + u < end) ? 1.f : 0.f;
                    else                  wg[u] = (j + u < end) ? dinv[s[u]] : 0.f;
                    hv[u] = h4[(size_t)s[u] * 16 + lane];
                }
#pragma unroll
                for (int u = 0; u < UN; ++u) {
                    float wu = IN_PRE ? wg[u] : wg[u] * dv;
                    float2 g0 = __half22float2(*(__half2*)&hv[u].x);
                    float2 g1 = __half22float2(*(__half2*)&hv[u].y);
                    float2 g2 = __half22float2(*(__half2*)&hv[u].z);
                    float2 g3 = __half22float2(*(__half2*)&hv[u].w);
                    a0 = fmaf(g0.x, wu, a0); a1 = fmaf(g0.y, wu, a1);
                    a2 = fmaf(g1.x, wu, a2); a3 = fmaf(g1.y, wu, a3);
                    a4 = fmaf(g2.x, wu, a4); a5 = fmaf(g2.y, wu, a5);
                    a6 = fmaf(g3.x, wu, a6); a7 = fmaf(g3.y, wu, a7);
                }
            }
            if constexpr (IN_PRE) {
                a0 *= dv; a1 *= dv; a2 *= dv; a3 *= dv;
                a4 *= dv; a5 *= dv; a6 *= dv; a7 *= dv;
            }
            float4 b0 = *(const float4*)&biasA[lane * 8];
            float4 b1 = *(const float4*)&biasA[lane * 8 + 4];
            a0 = fmaxf(a0 + b0.x, 0.f); a1 = fmaxf(a1 + b0.y, 0.f);
            a2 = fmaxf(a2 + b0.z, 0.f); a3 = fmaxf(a3 + b0.w, 0.f);
            a4 = fmaxf(a4 + b1.x, 0.f); a5 = fmaxf(a5 + b1.y, 0.f);
            a6 = fmaxf(a6 + b1.z, 0.f); a7 = fmaxf(a7 + b1.w, 0.f);
            __half2 o0 = __floats2half2_rn(a0, a1);
            __half2 o1 = __floats2half2_rn(a2, a3);
            __half2 o2 = __floats2half2_rn(a4, a5);
            __half2 o3 = __floats2half2_rn(a6, a7);
            *(int4*)&hs[row * 256 + bo] =
                make_int4(*(int*)&o0, *(int*)&o1, *(int*)&o2, *(int*)&o3);
        } else {
            *(int4*)&hs[row * 256 + bo] = make_int4(0, 0, 0, 0);
        }
    }
    __syncthreads();

    // ---- phase 2: 16-row GEMM from LDS ----
    constexpr int NW = N2 / 4;
    constexpr int NC = NW / 16;
    const int w = t >> 6, l = t & 63;
    const int lr = l & 15, kg = l >> 4;

    half8 wf[NC][4];
#pragma unroll
    for (int c = 0; c < NC; ++c)
#pragma unroll
        for (int ks = 0; ks < 4; ++ks)
            wf[c][ks] = *(const half8*)&Wt[(size_t)(w * NW + c * 16 + lr) * 128 +
                                           ks * 32 + kg * 8];

    half8 af[4];
#pragma unroll
    for (int ks = 0; ks < 4; ++ks) {
        int bo = (ks * 64 + kg * 16) ^ ((lr & 7) << 4);
        af[ks] = *(const half8*)&hs[lr * 256 + bo];
    }

    f32x4 acc[NC];
#pragma unroll
    for (int c = 0; c < NC; ++c) acc[c] = (f32x4){0.f, 0.f, 0.f, 0.f};
#pragma unroll
    for (int ks = 0; ks < 4; ++ks)
#pragma unroll
        for (int c = 0; c < NC; ++c)
            acc[c] = __builtin_amdgcn_mfma_f32_16x16x32_f16(wf[c][ks], af[ks], acc[c], 0, 0, 0);

    int row = node0 + lr;
    if (row < n) {
        float dvr = OUT_PRE ? dinv[row] : 1.f;
#pragma unroll
        for (int c = 0; c < NC; ++c) {
            int col = w * NW + c * 16 + kg * 4;
            float v0 = acc[c][0], v1 = acc[c][1], v2 = acc[c][2], v3 = acc[c][3];
            if constexpr (EPI) {
                float4 bv = *(const float4*)&biasG[col];
                v0 = fmaxf(v0 + bv.x, 0.f);
                v1 = fmaxf(v1 + bv.y, 0.f);
                v2 = fmaxf(v2 + bv.z, 0.f);
                v3 = fmaxf(v3 + bv.w, 0.f);
            }
            if constexpr (OUT_PRE) { v0 *= dvr; v1 *= dvr; v2 *= dvr; v3 *= dvr; }
            if constexpr (std::is_same_v<OT, float>) {
                *(float4*)&C[(size_t)row * N2 + col] = make_float4(v0, v1, v2, v3);
            } else {
                __half2 p0 = __floats2half2_rn(v0, v1);
                __half2 p1 = __floats2half2_rn(v2, v3);
                *(int2*)&C[(size_t)row * N2 + col] = make_int2(*(int*)&p0, *(int*)&p1);
            }
        }
    }
}

extern "C" void kernel_launch(void* const* d_in, const int* in_sizes, int n_in,
                              void* d_out, int out_size, void* d_ws, size_t ws_size,
                              hipStream_t stream) {
    const float* x  = (const float*)d_in[0];
    const int* ei   = (const int*)d_in[1];
    const float* W1 = (const float*)d_in[2];
    const float* b1 = (const float*)d_in[3];
    const float* W2 = (const float*)d_in[4];
    const float* b2 = (const float*)d_in[5];
    const float* W3 = (const float*)d_in[6];
    const float* b3 = (const float*)d_in[7];
    float* out = (float*)d_out;

    const int N = in_sizes[0] / 128;
    const int E = in_sizes[1] / 2;
    const int* esrc = ei;
    const int* edst = ei + E;
    const int nb = (N + 255) >> 8;  // 196 buckets (must be <=256)

    char* w = (char*)d_ws;
    size_t off = 0;
    auto alloc = [&](size_t bytes) {
        void* p = w + off;
        off = (off + bytes + 255) & ~(size_t)255;
        return p;
    };
    int*    gcount  = (int*)alloc((size_t)nb * 4);
    int2*   gbucket = (int2*)alloc((size_t)nb * CAP * 8);
    int*    offs    = (int*)alloc((size_t)(N + 1) * 4);
    float*  dinv    = (float*)alloc((size_t)N * 4);
    int*    eidx    = (int*)alloc((size_t)E * 4);
    __half* w1t     = (__half*)alloc(128 * 128 * 2);
    __half* w2t     = (__half*)alloc(128 * 128 * 2);
    __half* w3t     = (__half*)alloc(64 * 128 * 2);
    __half* g1buf   = (__half*)alloc((size_t)N * 128 * 2);
    __half* g2buf   = (__half*)alloc((size_t)N * 128 * 2);
    (void)ws_size;

    const int gemm_blocks = (N + 63) / 64;  // 782
    const int agg_blocks = (N + 15) / 16;   // 3125

    prep<<<160, 256, 0, stream>>>(W1, W2, W3, w1t, w2t, w3t, gcount, nb);
    bucket_p1<<<(E + 8191) / 8192, 1024, 0, stream>>>(esrc, edst, gcount, gbucket, nb, E);
    build_and_g1<<<nb + gemm_blocks, 256, 0, stream>>>(gcount, gbucket, offs, dinv,
                                                       eidx, x, w1t, g1buf, N, nb);
    // layer1: weighted agg + xW2; output rows *= dinv (pre-scale for layer2)
    agg_gemm<128, false, __half, false, true><<<agg_blocks, 256, 0, stream>>>(
        g1buf, dinv, offs, eidx, b1, w2t, nullptr, g2buf, N);
    // layer2: pure-add agg + xW3 + b3 + relu -> fp32 out
    agg_gemm<64, true, float, true, false><<<agg_blocks, 256, 0, stream>>>(
        g2buf, dinv, offs, eidx, b2, w3t, b3, out, N);
}